// Round 2
// baseline (34.259 us; speedup 1.0000x reference)
//
#include <hip/hip_runtime.h>
#include <hip/hip_cooperative_groups.h>
#include <math.h>

namespace cg = cooperative_groups;

// Problem constants (from setup_inputs): x [B,N,3], y [B,3,N], alt unused.
#define BN    4096                 // N
#define BB    8                    // B
#define NBLK  32                   // blocks (co-resident: 32 << 256 CUs)
#define TB    256                  // threads per block
#define TOTAL (BB * BN)            // 32768 (b,n) items
#define ITEMS (TOTAL / (NBLK * TB))// 4 items per thread

// Single cooperative kernel: phase 1 computes per-block partial sums of
// w(n) * ||x[b,n,:] - y[b,:,n]||; grid.sync(); phase 2 (block 0, wave 0)
// reduces the 32 partials and writes mean.
__global__ __launch_bounds__(TB) void diag_loss(
    const float* __restrict__ x,       // [B, N, 3]
    const float* __restrict__ y,       // [B, 3, N]
    float* __restrict__ partial,       // [NBLK] scratch (d_ws)
    float* __restrict__ out)           // [1]
{
    int tid = blockIdx.x * TB + threadIdx.x;

    float s = 0.0f;
    #pragma unroll
    for (int it = 0; it < ITEMS; ++it) {
        int idx = tid + it * (NBLK * TB);
        int n = idx & (BN - 1);
        int b = idx >> 12;                         // idx / 4096

        const float* xp = x + ((size_t)b * BN + n) * 3;
        const float* yp = y + (size_t)b * 3 * BN + n;
        float d0 = xp[0] - yp[0];
        float d1 = xp[1] - yp[BN];
        float d2 = xp[2] - yp[2 * BN];
        float d = sqrtf(d0 * d0 + d1 * d1 + d2 * d2);
        if (n == 1 || n == 2) d *= 1.5f;           // diag[1:3] *= 1.5
        s += d;
    }

    // wave (64-lane) reduction
    #pragma unroll
    for (int off = 32; off > 0; off >>= 1)
        s += __shfl_down(s, off, 64);

    __shared__ float lds[TB / 64];
    int lane = threadIdx.x & 63;
    int wid  = threadIdx.x >> 6;
    if (lane == 0) lds[wid] = s;
    __syncthreads();

    if (threadIdx.x == 0) {
        float t = 0.0f;
        #pragma unroll
        for (int i = 0; i < TB / 64; ++i) t += lds[i];
        partial[blockIdx.x] = t;
    }

    __threadfence();          // device-scope: partials visible cross-XCD
    cg::this_grid().sync();   // grid-wide barrier (cooperative launch)

    if (blockIdx.x == 0 && threadIdx.x < 64) {
        float v = (threadIdx.x < NBLK) ? partial[threadIdx.x] : 0.0f;
        #pragma unroll
        for (int off = 32; off > 0; off >>= 1)
            v += __shfl_down(v, off, 64);
        if (threadIdx.x == 0)
            out[0] = v * (1.0f / ((float)BB * (float)BN));
    }
}

extern "C" void kernel_launch(void* const* d_in, const int* in_sizes, int n_in,
                              void* d_out, int out_size, void* d_ws, size_t ws_size,
                              hipStream_t stream) {
    const float* x = (const float*)d_in[0];   // [8, 4096, 3]
    const float* y = (const float*)d_in[1];   // [8, 3, 4096]
    // d_in[2] (alt) is dead code in the reference.

    float* partial = (float*)d_ws;            // NBLK floats of scratch
    float* out     = (float*)d_out;           // 1 float

    void* args[] = { (void*)&x, (void*)&y, (void*)&partial, (void*)&out };
    hipLaunchCooperativeKernel((const void*)diag_loss,
                               dim3(NBLK), dim3(TB), args, 0, stream);
}

// Round 3
// 13.503 us; speedup vs baseline: 2.5372x; 2.5372x over previous
//
#include <hip/hip_runtime.h>
#include <math.h>

// Problem: diag-only of batched cdist. x [B,N,3] f32, y [B,3,N] f32, alt dead.
// out = mean_n ( w(n) * mean_b ||x[b,n,:] - y[b,:,n]|| ), w(1)=w(2)=1.5 else 1.
// B=8, N=4096 -> 32768 items, 786 KB of input. Launch-overhead bound:
// single kernel node, single workgroup (1024 thr = 16 waves on one CU),
// fully deterministic fixed-order reduction, no scratch, no atomics.

#define BN     4096
#define BB     8
#define TB     1024
#define NGRP   8192            // 32768 items in groups of 4
#define GPT    (NGRP / TB)     // 8 groups per thread

__global__ __launch_bounds__(TB) void diag_loss_single(
    const float* __restrict__ x,   // [B, N, 3]
    const float* __restrict__ y,   // [B, 3, N]
    float* __restrict__ out)       // [1]
{
    int t = threadIdx.x;
    float s = 0.0f;

    #pragma unroll 2
    for (int it = 0; it < GPT; ++it) {
        int g  = t + it * TB;          // group id, 4 consecutive items
        int b  = g >> 10;              // (4g)/4096
        int n0 = (g & 1023) << 2;      // (4g)%4096

        // x: 4 items = 12 consecutive floats = 3 float4 (48B-aligned)
        const float4* xp = (const float4*)(x + (size_t)g * 12);
        float4 xa = xp[0], xb = xp[1], xc = xp[2];

        // y: 3 rows of 4 consecutive floats (16B-aligned)
        const float* ybase = y + (size_t)b * 3 * BN + n0;
        float4 y0 = *(const float4*)(ybase);
        float4 y1 = *(const float4*)(ybase + BN);
        float4 y2 = *(const float4*)(ybase + 2 * BN);

        // item 0: x(xa.x,xa.y,xa.z)  y(y0.x,y1.x,y2.x)
        float d0 = xa.x - y0.x, d1 = xa.y - y1.x, d2 = xa.z - y2.x;
        float r0 = sqrtf(d0 * d0 + d1 * d1 + d2 * d2);
        // item 1
        d0 = xa.w - y0.y; d1 = xb.x - y1.y; d2 = xb.y - y2.y;
        float r1 = sqrtf(d0 * d0 + d1 * d1 + d2 * d2);
        // item 2
        d0 = xb.z - y0.z; d1 = xb.w - y1.z; d2 = xc.x - y2.z;
        float r2 = sqrtf(d0 * d0 + d1 * d1 + d2 * d2);
        // item 3
        d0 = xc.y - y0.w; d1 = xc.z - y1.w; d2 = xc.w - y2.w;
        float r3 = sqrtf(d0 * d0 + d1 * d1 + d2 * d2);

        // diag[1:3] *= 1.5 : only groups with n0==0 contain n=1,2
        if (n0 == 0) { r1 *= 1.5f; r2 *= 1.5f; }

        s += (r0 + r1) + (r2 + r3);
    }

    // wave (64-lane) reduction
    #pragma unroll
    for (int off = 32; off > 0; off >>= 1)
        s += __shfl_down(s, off, 64);

    __shared__ float lds[TB / 64];   // 16 wave partials
    int lane = t & 63;
    int wid  = t >> 6;
    if (lane == 0) lds[wid] = s;
    __syncthreads();

    if (t < 64) {
        float v = (t < TB / 64) ? lds[t] : 0.0f;
        #pragma unroll
        for (int off = 8; off > 0; off >>= 1)
            v += __shfl_down(v, off, 64);
        if (t == 0)
            out[0] = v * (1.0f / ((float)BB * (float)BN));
    }
}

extern "C" void kernel_launch(void* const* d_in, const int* in_sizes, int n_in,
                              void* d_out, int out_size, void* d_ws, size_t ws_size,
                              hipStream_t stream) {
    const float* x = (const float*)d_in[0];   // [8, 4096, 3]
    const float* y = (const float*)d_in[1];   // [8, 3, 4096]
    // d_in[2] (alt) is dead code in the reference.

    diag_loss_single<<<1, TB, 0, stream>>>(x, y, (float*)d_out);
}

// Round 4
// 9.262 us; speedup vs baseline: 3.6989x; 1.4579x over previous
//
#include <hip/hip_runtime.h>
#include <math.h>

// diag-only of batched cdist: out = mean_{b,n} w(n)*||x[b,n,:]-y[b,:,n]||,
// w(1)=w(2)=1.5 else 1.  x [8,4096,3] f32, y [8,3,4096] f32, alt dead.
// Single kernel node, 32 blocks (multi-CU exec), deterministic in-kernel
// cross-block combine via self-validating tokens (no pre-zeroed flags,
// no atomically-ordered float math, no state carried across calls).

#define BN   4096
#define BB   8
#define NB   32     // blocks
#define TB   256    // threads per block
#define HASH 0x9E3779B9u

__global__ __launch_bounds__(TB) void diag_loss_fused(
    const float* __restrict__ x,     // [B, N, 3]
    const float* __restrict__ y,     // [B, 3, N]
    unsigned* __restrict__ ws,       // [0..NB): partial bits, [NB..2NB): tokens
    float* __restrict__ out)         // [1]
{
    int t   = threadIdx.x;
    int blk = blockIdx.x;
    int g   = blk * TB + t;            // group id 0..8191; 4 items per group
    int b   = g >> 10;                 // batch
    int n0  = (g & 1023) << 2;         // first n of this group

    // x: 4 items = 12 consecutive floats = 3 float4 (48B stride, 16B aligned)
    const float4* xp = (const float4*)(x + (size_t)g * 12);
    float4 xa = xp[0], xb = xp[1], xc = xp[2];

    // y: 3 rows of 4 consecutive floats
    const float* ybase = y + (size_t)b * 3 * BN + n0;
    float4 y0 = *(const float4*)(ybase);
    float4 y1 = *(const float4*)(ybase + BN);
    float4 y2 = *(const float4*)(ybase + 2 * BN);

    float d0 = xa.x - y0.x, d1 = xa.y - y1.x, d2 = xa.z - y2.x;
    float r0 = sqrtf(d0 * d0 + d1 * d1 + d2 * d2);
    d0 = xa.w - y0.y; d1 = xb.x - y1.y; d2 = xb.y - y2.y;
    float r1 = sqrtf(d0 * d0 + d1 * d1 + d2 * d2);
    d0 = xb.z - y0.z; d1 = xb.w - y1.z; d2 = xc.x - y2.z;
    float r2 = sqrtf(d0 * d0 + d1 * d1 + d2 * d2);
    d0 = xc.y - y0.w; d1 = xc.z - y1.w; d2 = xc.w - y2.w;
    float r3 = sqrtf(d0 * d0 + d1 * d1 + d2 * d2);

    if (n0 == 0) { r1 *= 1.5f; r2 *= 1.5f; }   // n==1,2 weighted, every b
    float s = (r0 + r1) + (r2 + r3);

    // wave reduction (64 lanes)
    #pragma unroll
    for (int off = 32; off > 0; off >>= 1)
        s += __shfl_down(s, off, 64);

    __shared__ float lds[TB / 64];
    int lane = t & 63, wid = t >> 6;
    if (lane == 0) lds[wid] = s;
    __syncthreads();

    if (t == 0) {
        float p = (lds[0] + lds[1]) + (lds[2] + lds[3]);
        unsigned bits = __float_as_uint(p);
        __hip_atomic_store(&ws[blk], bits,
                           __ATOMIC_RELAXED, __HIP_MEMORY_SCOPE_AGENT);
        __hip_atomic_store(&ws[NB + blk], bits ^ (HASH * (unsigned)(blk + 1)),
                           __ATOMIC_RELEASE, __HIP_MEMORY_SCOPE_AGENT);
    }

    // block 0, wave 0: lane i waits for block i's token, then fixed-order reduce
    if (blk == 0 && t < 64) {
        float v = 0.0f;
        if (t < NB) {
            unsigned tok, bits;
            for (;;) {
                tok  = __hip_atomic_load(&ws[NB + t],
                                         __ATOMIC_ACQUIRE, __HIP_MEMORY_SCOPE_AGENT);
                bits = __hip_atomic_load(&ws[t],
                                         __ATOMIC_RELAXED, __HIP_MEMORY_SCOPE_AGENT);
                if (tok == (bits ^ (HASH * (unsigned)(t + 1)))) break;
                __builtin_amdgcn_s_sleep(1);
            }
            v = __uint_as_float(bits);
        }
        #pragma unroll
        for (int off = 16; off > 0; off >>= 1)
            v += __shfl_down(v, off, 64);
        if (t == 0)
            out[0] = v * (1.0f / ((float)BB * (float)BN));
    }
}

extern "C" void kernel_launch(void* const* d_in, const int* in_sizes, int n_in,
                              void* d_out, int out_size, void* d_ws, size_t ws_size,
                              hipStream_t stream) {
    const float* x = (const float*)d_in[0];   // [8, 4096, 3]
    const float* y = (const float*)d_in[1];   // [8, 3, 4096]
    // d_in[2] (alt) is dead code in the reference.

    diag_loss_fused<<<NB, TB, 0, stream>>>(x, y, (unsigned*)d_ws, (float*)d_out);
}